// Round 2
// baseline (1967.979 us; speedup 1.0000x reference)
//
#include <hip/hip_runtime.h>
#include <math.h>

#define N_NODES 50000
#define N_EDGES 800000
#define IN_DIM  16
#define HID     64
#define NH      4
#define NGRAPH  128
#define OUT_DIM 32
#define NUM_LAYERS 8
#define NEG_SLOPE 0.2f

#define SCAN_BLOCKS ((N_NODES + 255) / 256)   // 196

// ---------------- setup kernels ----------------

// Concatenate W_src|W_dst into Wcat[128][512], b_src|b_dst into bcat[512]
__global__ void k_build_w(const float* __restrict__ Wsrc, const float* __restrict__ bsrc,
                          const float* __restrict__ Wdst, const float* __restrict__ bdst,
                          float* __restrict__ Wcat, float* __restrict__ bcat) {
    int i = blockIdx.x * 256 + threadIdx.x;
    if (i < 128 * 512) {
        int k = i >> 9, j = i & 511;
        Wcat[i] = (j < 256) ? Wsrc[k * 256 + j] : Wdst[k * 256 + (j - 256)];
    }
    if (i < 512) bcat[i] = (i < 256) ? bsrc[i] : bdst[i - 256];
}

__global__ void k_hist(const int* __restrict__ dst, int* __restrict__ deg) {
    int e = blockIdx.x * 256 + threadIdx.x;
    if (e < N_EDGES) atomicAdd(&deg[dst[e]], 1);
}

__global__ void k_blocksum(const int* __restrict__ deg, int* __restrict__ bsum) {
    __shared__ int sm[256];
    int i = blockIdx.x * 256 + threadIdx.x;
    sm[threadIdx.x] = (i < N_NODES) ? deg[i] : 0;
    __syncthreads();
    for (int s = 128; s > 0; s >>= 1) {
        if (threadIdx.x < s) sm[threadIdx.x] += sm[threadIdx.x + s];
        __syncthreads();
    }
    if (threadIdx.x == 0) bsum[blockIdx.x] = sm[0];
}

__global__ void k_scanbsum(int* __restrict__ bsum) {
    if (threadIdx.x == 0 && blockIdx.x == 0) {
        int acc = 0;
        for (int b = 0; b < SCAN_BLOCKS; b++) { int t = bsum[b]; bsum[b] = acc; acc += t; }
    }
}

__global__ void k_rowptr(const int* __restrict__ deg, const int* __restrict__ bsum,
                         int* __restrict__ row_ptr) {
    __shared__ int sm[256];
    int i = blockIdx.x * 256 + threadIdx.x;
    int v = (i < N_NODES) ? deg[i] : 0;
    sm[threadIdx.x] = v;
    __syncthreads();
    for (int s = 1; s < 256; s <<= 1) {
        int t = (threadIdx.x >= (unsigned)s) ? sm[threadIdx.x - s] : 0;
        __syncthreads();
        sm[threadIdx.x] += t;
        __syncthreads();
    }
    if (i < N_NODES) row_ptr[i] = bsum[blockIdx.x] + sm[threadIdx.x] - v;  // exclusive
}

__global__ void k_scatter(const int* __restrict__ src, const int* __restrict__ dst,
                          const int* __restrict__ row_ptr, int* __restrict__ cursor,
                          int* __restrict__ csr_src) {
    int e = blockIdx.x * 256 + threadIdx.x;
    if (e < N_EDGES) {
        int d = dst[e];
        int pos = atomicAdd(&cursor[d], 1);
        csr_src[row_ptr[d] + pos] = src[e];
    }
}

// h0 = feat @ W_in + b_in   [50000,16]@[16,64]; one wave per node, lane = out col
__global__ __launch_bounds__(256) void k_in_gemm(const float* __restrict__ feat,
                                                 const float* __restrict__ W,
                                                 const float* __restrict__ b,
                                                 float* __restrict__ h0) {
    __shared__ float sW[IN_DIM * HID];
    __shared__ float sb[HID];
    int t = threadIdx.x;
    for (int i = t; i < IN_DIM * HID; i += 256) sW[i] = W[i];
    if (t < HID) sb[t] = b[t];
    __syncthreads();
    int wid = (blockIdx.x * 256 + t) >> 6;   // node
    int lane = t & 63;
    const float* f = feat + wid * IN_DIM;
    float acc = sb[lane];
    #pragma unroll
    for (int k = 0; k < IN_DIM; k++) acc += f[k] * sW[k * HID + lane];
    h0[wid * HID + lane] = acc;
}

// ---------------- per-layer kernels ----------------

// fsfd[N][512] = [h|h0] @ Wcat + bcat.  BM=64,BN=64,BK=16, 256 thr, 4x4 microtile.
__global__ __launch_bounds__(256) void k_gemm_fsfd(const float* __restrict__ h,
                                                   const float* __restrict__ h0,
                                                   const float* __restrict__ Wcat,
                                                   const float* __restrict__ bcat,
                                                   float* __restrict__ fsfd) {
    __shared__ float As[16][68];
    __shared__ float Bs[16][68];
    int bx = blockIdx.x & 7;           // col tile (512/64 = 8)
    int by = blockIdx.x >> 3;          // row tile
    int row0 = by * 64, col0 = bx * 64;
    int tid = threadIdx.x;
    int tx = tid & 15, ty = tid >> 4;
    float acc[4][4] = {};

    int lr = tid >> 2, lk = (tid & 3) * 4;     // A-load: row, k4
    int br = tid >> 4, bc = (tid & 15) * 4;    // B-load: k-row, col4

    for (int kk = 0; kk < 128; kk += 16) {
        const float* Aptr = (kk < 64) ? h : h0;
        int ka = kk & 63;
        int grow = row0 + lr;
        float4 av = make_float4(0.f, 0.f, 0.f, 0.f);
        if (grow < N_NODES) av = *(const float4*)(Aptr + grow * HID + ka + lk);
        As[lk + 0][lr] = av.x; As[lk + 1][lr] = av.y;
        As[lk + 2][lr] = av.z; As[lk + 3][lr] = av.w;
        *(float4*)&Bs[br][bc] = *(const float4*)(Wcat + (kk + br) * 512 + col0 + bc);
        __syncthreads();
        #pragma unroll
        for (int k = 0; k < 16; k++) {
            float a0 = As[k][ty * 4 + 0], a1 = As[k][ty * 4 + 1];
            float a2 = As[k][ty * 4 + 2], a3 = As[k][ty * 4 + 3];
            float4 bv = *(const float4*)&Bs[k][tx * 4];
            acc[0][0] += a0 * bv.x; acc[0][1] += a0 * bv.y; acc[0][2] += a0 * bv.z; acc[0][3] += a0 * bv.w;
            acc[1][0] += a1 * bv.x; acc[1][1] += a1 * bv.y; acc[1][2] += a1 * bv.z; acc[1][3] += a1 * bv.w;
            acc[2][0] += a2 * bv.x; acc[2][1] += a2 * bv.y; acc[2][2] += a2 * bv.z; acc[2][3] += a2 * bv.w;
            acc[3][0] += a3 * bv.x; acc[3][1] += a3 * bv.y; acc[3][2] += a3 * bv.z; acc[3][3] += a3 * bv.w;
        }
        __syncthreads();
    }
    float4 bias = *(const float4*)(bcat + col0 + tx * 4);
    #pragma unroll
    for (int i = 0; i < 4; i++) {
        int r = row0 + ty * 4 + i;
        if (r < N_NODES) {
            float4 o;
            o.x = acc[i][0] + bias.x; o.y = acc[i][1] + bias.y;
            o.z = acc[i][2] + bias.z; o.w = acc[i][3] + bias.w;
            *(float4*)(fsfd + (size_t)r * 512 + col0 + tx * 4) = o;
        }
    }
}

// Per dst node: online segment-softmax + weighted aggregation + tanh-headsum.
// One wave per node. lane -> head h = lane>>4, dims d0=(lane&15)*4 .. +3
__global__ __launch_bounds__(256) void k_edge(const float* __restrict__ fsfd,
                                              const float* __restrict__ attn,
                                              const int* __restrict__ row_ptr,
                                              const int* __restrict__ deg,
                                              const int* __restrict__ csr_src,
                                              float* __restrict__ h) {
    int wid = (blockIdx.x * 256 + threadIdx.x) >> 6;   // node (grid exact: 50000 waves)
    int lane = threadIdx.x & 63;
    int hh = lane >> 4;
    int d0 = (lane & 15) * 4;

    const float4 an  = *(const float4*)(attn + hh * HID + d0);
    const float4 fdv = *(const float4*)(fsfd + (size_t)wid * 512 + 256 + hh * HID + d0);

    float m = -INFINITY, denom = 0.f;
    float4 agg = make_float4(0.f, 0.f, 0.f, 0.f);

    int r0 = row_ptr[wid], dg = deg[wid];
    for (int i = 0; i < dg; i++) {
        int s = csr_src[r0 + i];
        float4 fsv = *(const float4*)(fsfd + (size_t)s * 512 + hh * HID + d0);
        float e0 = fsv.x + fdv.x, e1 = fsv.y + fdv.y, e2 = fsv.z + fdv.z, e3 = fsv.w + fdv.w;
        e0 = fmaxf(e0, 0.f) + NEG_SLOPE * fminf(e0, 0.f);
        e1 = fmaxf(e1, 0.f) + NEG_SLOPE * fminf(e1, 0.f);
        e2 = fmaxf(e2, 0.f) + NEG_SLOPE * fminf(e2, 0.f);
        e3 = fmaxf(e3, 0.f) + NEG_SLOPE * fminf(e3, 0.f);
        float p = e0 * an.x + e1 * an.y + e2 * an.z + e3 * an.w;
        p += __shfl_xor(p, 1); p += __shfl_xor(p, 2);
        p += __shfl_xor(p, 4); p += __shfl_xor(p, 8);   // sum over this head's 16 lanes
        float nm = fmaxf(m, p);
        float rs = __expf(m - nm);       // 0 when m = -inf
        float c  = __expf(p - nm);
        agg.x = agg.x * rs + c * fsv.x;
        agg.y = agg.y * rs + c * fsv.y;
        agg.z = agg.z * rs + c * fsv.z;
        agg.w = agg.w * rs + c * fsv.w;
        denom = denom * rs + c;
        m = nm;
    }
    float inv = denom > 0.f ? 1.f / denom : 0.f;
    float t0 = tanhf(agg.x * inv), t1 = tanhf(agg.y * inv);
    float t2 = tanhf(agg.z * inv), t3 = tanhf(agg.w * inv);
    // sum over 4 heads (lanes l, l^16, l^32, l^48 share the same dims)
    t0 += __shfl_xor(t0, 16); t0 += __shfl_xor(t0, 32);
    t1 += __shfl_xor(t1, 16); t1 += __shfl_xor(t1, 32);
    t2 += __shfl_xor(t2, 16); t2 += __shfl_xor(t2, 32);
    t3 += __shfl_xor(t3, 16); t3 += __shfl_xor(t3, 32);
    if (lane < 16) {
        float4 o = make_float4(t0, t1, t2, t3);
        *(float4*)(h + (size_t)wid * HID + d0) = o;
    }
}

// ---------------- readout ----------------

__global__ __launch_bounds__(256) void k_readout(const float* __restrict__ h,
                                                 const int* __restrict__ graph_ids,
                                                 const int* __restrict__ is_root,
                                                 float* __restrict__ hg) {
    int wid = (blockIdx.x * 256 + threadIdx.x) >> 6;
    int lane = threadIdx.x & 63;
    if (is_root[wid]) {
        int g = graph_ids[wid];
        atomicAdd(&hg[g * HID + lane], h[(size_t)wid * HID + lane]);
    }
}

__global__ void k_out_gemm(const float* __restrict__ hg, const float* __restrict__ W,
                           const float* __restrict__ b, float* __restrict__ out) {
    int i = blockIdx.x * 256 + threadIdx.x;
    if (i >= NGRAPH * OUT_DIM) return;
    int g = i >> 5, o = i & 31;
    float acc = b[o];
    #pragma unroll
    for (int k = 0; k < HID; k++) acc += hg[g * HID + k] * W[k * OUT_DIM + o];
    out[i] = acc;
}

// ---------------- host ----------------

extern "C" void kernel_launch(void* const* d_in, const int* in_sizes, int n_in,
                              void* d_out, int out_size, void* d_ws, size_t ws_size,
                              hipStream_t stream) {
    const float* feat      = (const float*)d_in[0];
    const int*   src       = (const int*)d_in[1];
    const int*   dst       = (const int*)d_in[2];
    const int*   graph_ids = (const int*)d_in[3];
    const int*   is_root   = (const int*)d_in[4];
    const float* W_in      = (const float*)d_in[5];
    const float* b_in      = (const float*)d_in[6];
    const float* W_src     = (const float*)d_in[7];
    const float* b_src     = (const float*)d_in[8];
    const float* W_dst     = (const float*)d_in[9];
    const float* b_dst     = (const float*)d_in[10];
    const float* attn      = (const float*)d_in[11];
    const float* W_out     = (const float*)d_in[12];
    const float* b_out     = (const float*)d_in[13];
    float* out = (float*)d_out;

    char* base = (char*)d_ws;
    size_t off = 0;
    auto carve = [&](size_t bytes) -> char* {
        char* p = base + off;
        off = (off + bytes + 255) & ~(size_t)255;
        return p;
    };
    float* h0      = (float*)carve((size_t)N_NODES * HID * 4);
    float* h       = (float*)carve((size_t)N_NODES * HID * 4);
    float* fsfd    = (float*)carve((size_t)N_NODES * 512 * 4);
    float* Wcat    = (float*)carve(128 * 512 * 4);
    float* bcat    = (float*)carve(512 * 4);
    int*   csr_src = (int*)carve((size_t)N_EDGES * 4);
    int*   row_ptr = (int*)carve((size_t)N_NODES * 4);
    int*   bsum    = (int*)carve(SCAN_BLOCKS * 4);
    char*  zero0   = carve(0);
    int*   deg     = (int*)carve((size_t)N_NODES * 4);
    int*   cursor  = (int*)carve((size_t)N_NODES * 4);
    float* hg      = (float*)carve((size_t)NGRAPH * HID * 4);
    char*  zero1   = base + off;
    if (off > ws_size) return;  // workspace too small -> fail loudly

    hipMemsetAsync(zero0, 0, (size_t)(zero1 - zero0), stream);

    // graph prep
    k_build_w<<<256, 256, 0, stream>>>(W_src, b_src, W_dst, b_dst, Wcat, bcat);
    k_hist<<<(N_EDGES + 255) / 256, 256, 0, stream>>>(dst, deg);
    k_blocksum<<<SCAN_BLOCKS, 256, 0, stream>>>(deg, bsum);
    k_scanbsum<<<1, 64, 0, stream>>>(bsum);
    k_rowptr<<<SCAN_BLOCKS, 256, 0, stream>>>(deg, bsum, row_ptr);
    k_scatter<<<(N_EDGES + 255) / 256, 256, 0, stream>>>(src, dst, row_ptr, cursor, csr_src);

    // input projection
    k_in_gemm<<<N_NODES / 4, 256, 0, stream>>>(feat, W_in, b_in, h0);

    const int gemm_grid = ((N_NODES + 63) / 64) * 8;   // 782 * 8
    for (int layer = 0; layer < NUM_LAYERS; layer++) {
        const float* hcur = (layer == 0) ? h0 : h;
        k_gemm_fsfd<<<gemm_grid, 256, 0, stream>>>(hcur, h0, Wcat, bcat, fsfd);
        k_edge<<<N_NODES / 4, 256, 0, stream>>>(fsfd, attn, row_ptr, deg, csr_src, h);
    }

    k_readout<<<N_NODES / 4, 256, 0, stream>>>(h, graph_ids, is_root, hg);
    k_out_gemm<<<(NGRAPH * OUT_DIM + 255) / 256, 256, 0, stream>>>(hg, W_out, b_out, out);
}

// Round 3
// 1270.812 us; speedup vs baseline: 1.5486x; 1.5486x over previous
//
#include <hip/hip_runtime.h>
#include <math.h>

#define N_NODES 50000
#define N_EDGES 800000
#define IN_DIM  16
#define HID     64
#define NH      4
#define NGRAPH  128
#define OUT_DIM 32
#define NUM_LAYERS 8
#define NEG_SLOPE 0.2f

#define SCAN_BLOCKS ((N_NODES + 255) / 256)   // 196

typedef unsigned short u16;
typedef __attribute__((ext_vector_type(8))) short bf16x8;
typedef __attribute__((ext_vector_type(4))) float f32x4;

// float -> bf16 (round-nearest-even), bf16 -> float
static __device__ __forceinline__ u16 f2b(float f) {
    unsigned u = __float_as_uint(f);
    unsigned r = (u + 0x7fffu + ((u >> 16) & 1u)) >> 16;
    return (u16)r;
}
static __device__ __forceinline__ float b2f(u16 u) {
    return __uint_as_float(((unsigned)u) << 16);
}

// ---------------- setup kernels ----------------

// Pack Wcat=[W_src|W_dst] (fp32 [128][512]) into MFMA-fragment-ordered bf16:
// Wpack[((nt*4+kt)*64 + l)*8 + i] = Wcat[kt*32 + (l>>4)*8 + i][nt*16 + (l&15)]
// Also bcat[512] fp32.
__global__ void k_build_wpack(const float* __restrict__ Wsrc, const float* __restrict__ bsrc,
                              const float* __restrict__ Wdst, const float* __restrict__ bdst,
                              u16* __restrict__ Wpack, float* __restrict__ bcat) {
    int tid = blockIdx.x * 256 + threadIdx.x;   // 0..65535
    int i = tid & 7;
    int l = (tid >> 3) & 63;
    int rest = tid >> 9;          // 0..127
    int kt = rest & 3;
    int nt = rest >> 2;           // 0..31
    int k = kt * 32 + (l >> 4) * 8 + i;      // 0..127
    int col = nt * 16 + (l & 15);            // 0..511
    float v = (col < 256) ? Wsrc[k * 256 + col] : Wdst[k * 256 + (col - 256)];
    Wpack[tid] = f2b(v);
    if (tid < 512) bcat[tid] = (tid < 256) ? bsrc[tid] : bdst[tid - 256];
}

__global__ void k_hist(const int* __restrict__ dst, int* __restrict__ deg) {
    int e = blockIdx.x * 256 + threadIdx.x;
    if (e < N_EDGES) atomicAdd(&deg[dst[e]], 1);
}

__global__ void k_blocksum(const int* __restrict__ deg, int* __restrict__ bsum) {
    __shared__ int sm[256];
    int i = blockIdx.x * 256 + threadIdx.x;
    sm[threadIdx.x] = (i < N_NODES) ? deg[i] : 0;
    __syncthreads();
    for (int s = 128; s > 0; s >>= 1) {
        if (threadIdx.x < s) sm[threadIdx.x] += sm[threadIdx.x + s];
        __syncthreads();
    }
    if (threadIdx.x == 0) bsum[blockIdx.x] = sm[0];
}

__global__ void k_scanbsum(int* __restrict__ bsum) {
    if (threadIdx.x == 0 && blockIdx.x == 0) {
        int acc = 0;
        for (int b = 0; b < SCAN_BLOCKS; b++) { int t = bsum[b]; bsum[b] = acc; acc += t; }
    }
}

__global__ void k_rowptr(const int* __restrict__ deg, const int* __restrict__ bsum,
                         int* __restrict__ row_ptr) {
    __shared__ int sm[256];
    int i = blockIdx.x * 256 + threadIdx.x;
    int v = (i < N_NODES) ? deg[i] : 0;
    sm[threadIdx.x] = v;
    __syncthreads();
    for (int s = 1; s < 256; s <<= 1) {
        int t = (threadIdx.x >= (unsigned)s) ? sm[threadIdx.x - s] : 0;
        __syncthreads();
        sm[threadIdx.x] += t;
        __syncthreads();
    }
    if (i < N_NODES) row_ptr[i] = bsum[blockIdx.x] + sm[threadIdx.x] - v;  // exclusive
}

__global__ void k_scatter(const int* __restrict__ src, const int* __restrict__ dst,
                          const int* __restrict__ row_ptr, int* __restrict__ cursor,
                          int* __restrict__ csr_src) {
    int e = blockIdx.x * 256 + threadIdx.x;
    if (e < N_EDGES) {
        int d = dst[e];
        int pos = atomicAdd(&cursor[d], 1);
        csr_src[row_ptr[d] + pos] = src[e];
    }
}

// h0b = bf16(feat @ W_in + b_in)   one wave per node, lane = out col
__global__ __launch_bounds__(256) void k_in_gemm(const float* __restrict__ feat,
                                                 const float* __restrict__ W,
                                                 const float* __restrict__ b,
                                                 u16* __restrict__ h0b) {
    __shared__ float sW[IN_DIM * HID];
    __shared__ float sb[HID];
    int t = threadIdx.x;
    for (int i = t; i < IN_DIM * HID; i += 256) sW[i] = W[i];
    if (t < HID) sb[t] = b[t];
    __syncthreads();
    int wid = (blockIdx.x * 256 + t) >> 6;   // node
    int lane = t & 63;
    const float* f = feat + wid * IN_DIM;
    float acc = sb[lane];
    #pragma unroll
    for (int k = 0; k < IN_DIM; k++) acc += f[k] * sW[k * HID + lane];
    h0b[wid * HID + lane] = f2b(acc);
}

// ---------------- per-layer kernels ----------------

// fsfd[N][512] (bf16) = [h|h0] @ Wcat + bcat via MFMA 16x16x32 bf16.
// Block = 4 waves; wave w handles rows [wave_gid*16, +16), all 512 cols in
// 4 col-groups of 128. W fragments for the active col-group staged in LDS
// (32 KB, shared by all 4 waves); C tile repacked via per-wave LDS slice.
#define ST_STRIDE 152   // shorts per staged C row (304 B: 16B-aligned, bank-spread)
__global__ __launch_bounds__(256) void k_gemm_mfma(const u16* __restrict__ hb,
                                                   const u16* __restrict__ h0b,
                                                   const u16* __restrict__ Wpack,
                                                   const float* __restrict__ bcat,
                                                   u16* __restrict__ fsfd) {
    __shared__ u16 smem[16384];   // 32 KB: W-group fragments, then reused for C staging
    int tid = threadIdx.x;
    int l = tid & 63, w = tid >> 6;
    int lr = l & 15, lg = l >> 4;
    int wave_gid = blockIdx.x * 4 + w;
    size_t row0 = (size_t)wave_gid * 16;
    bool valid = (row0 < N_NODES);            // waves are fully in- or out-of-range (50000%16==0)
    u16* myst = smem + w * 4096;              // per-wave C staging slice (needs 16*152=2432)

    for (int g = 0; g < 4; g++) {
        __syncthreads();   // prior group's staging reads done before W overwrite
        // cooperative load of this col-group's W fragments (32 KB, contiguous)
        {
            const bf16x8* src = (const bf16x8*)(Wpack) + g * 2048;
            bf16x8* dst = (bf16x8*)smem;
            #pragma unroll
            for (int it = 0; it < 8; it++) dst[it * 256 + tid] = src[it * 256 + tid];
        }
        __syncthreads();

        f32x4 acc[8];
        #pragma unroll
        for (int nt = 0; nt < 8; nt++) acc[nt] = (f32x4){0.f, 0.f, 0.f, 0.f};

        size_t arow = valid ? (row0 + lr) : 0;
        #pragma unroll
        for (int kt = 0; kt < 4; kt++) {
            const u16* A = (kt < 2) ? hb : h0b;
            bf16x8 a = *(const bf16x8*)(A + arow * HID + (kt & 1) * 32 + lg * 8);
            #pragma unroll
            for (int nt = 0; nt < 8; nt++) {
                bf16x8 bfr = *(const bf16x8*)(smem + nt * 2048 + kt * 512 + l * 8);
                acc[nt] = __builtin_amdgcn_mfma_f32_16x16x32_bf16(a, bfr, acc[nt], 0, 0, 0);
            }
        }
        __syncthreads();   // all waves done reading W before staging overwrites it

        // C/D layout: acc[nt][j] = C[row0 + lg*4 + j][g*128 + nt*16 + lr]
        #pragma unroll
        for (int nt = 0; nt < 8; nt++) {
            float bv = bcat[g * 128 + nt * 16 + lr];
            #pragma unroll
            for (int j = 0; j < 4; j++)
                myst[(lg * 4 + j) * ST_STRIDE + nt * 16 + lr] = f2b(acc[nt][j] + bv);
        }
        // coalesced readback + store: iter j covers rows 4j+lg, 128 cols
        if (valid) {
            #pragma unroll
            for (int j = 0; j < 4; j++) {
                int rloc = j * 4 + lg;
                bf16x8 v = *(const bf16x8*)(myst + rloc * ST_STRIDE + lr * 8);
                *(bf16x8*)(fsfd + (row0 + rloc) * 512 + g * 128 + lr * 8) = v;
            }
        }
    }
}

// Per dst node: online segment-softmax + weighted aggregation + tanh-headsum.
// One wave per node. lane -> head hh = lane>>4, dims d0=(lane&15)*4 .. +3
__global__ __launch_bounds__(256) void k_edge(const u16* __restrict__ fsfd,
                                              const float* __restrict__ attn,
                                              const int* __restrict__ row_ptr,
                                              const int* __restrict__ deg,
                                              const int* __restrict__ csr_src,
                                              u16* __restrict__ h) {
    int wid = (blockIdx.x * 256 + threadIdx.x) >> 6;   // node (grid exact)
    int lane = threadIdx.x & 63;
    int hh = lane >> 4;
    int d0 = (lane & 15) * 4;

    const float4 an = *(const float4*)(attn + hh * HID + d0);
    ushort4 fdu = *(const ushort4*)(fsfd + (size_t)wid * 512 + 256 + hh * HID + d0);
    float fd0 = b2f(fdu.x), fd1 = b2f(fdu.y), fd2 = b2f(fdu.z), fd3 = b2f(fdu.w);

    float m = -INFINITY, denom = 0.f;
    float4 agg = make_float4(0.f, 0.f, 0.f, 0.f);

    int r0 = row_ptr[wid], dg = deg[wid];
    for (int i = 0; i < dg; i++) {
        int s = csr_src[r0 + i];
        ushort4 fsu = *(const ushort4*)(fsfd + (size_t)s * 512 + hh * HID + d0);
        float f0 = b2f(fsu.x), f1 = b2f(fsu.y), f2 = b2f(fsu.z), f3 = b2f(fsu.w);
        float e0 = f0 + fd0, e1 = f1 + fd1, e2 = f2 + fd2, e3 = f3 + fd3;
        e0 = fmaxf(e0, 0.f) + NEG_SLOPE * fminf(e0, 0.f);
        e1 = fmaxf(e1, 0.f) + NEG_SLOPE * fminf(e1, 0.f);
        e2 = fmaxf(e2, 0.f) + NEG_SLOPE * fminf(e2, 0.f);
        e3 = fmaxf(e3, 0.f) + NEG_SLOPE * fminf(e3, 0.f);
        float p = e0 * an.x + e1 * an.y + e2 * an.z + e3 * an.w;
        p += __shfl_xor(p, 1); p += __shfl_xor(p, 2);
        p += __shfl_xor(p, 4); p += __shfl_xor(p, 8);   // sum over head's 16 lanes
        float nm = fmaxf(m, p);
        float rs = __expf(m - nm);       // 0 when m = -inf
        float c  = __expf(p - nm);
        agg.x = agg.x * rs + c * f0;
        agg.y = agg.y * rs + c * f1;
        agg.z = agg.z * rs + c * f2;
        agg.w = agg.w * rs + c * f3;
        denom = denom * rs + c;
        m = nm;
    }
    float inv = denom > 0.f ? 1.f / denom : 0.f;
    float t0 = tanhf(agg.x * inv), t1 = tanhf(agg.y * inv);
    float t2 = tanhf(agg.z * inv), t3 = tanhf(agg.w * inv);
    // sum over 4 heads
    t0 += __shfl_xor(t0, 16); t0 += __shfl_xor(t0, 32);
    t1 += __shfl_xor(t1, 16); t1 += __shfl_xor(t1, 32);
    t2 += __shfl_xor(t2, 16); t2 += __shfl_xor(t2, 32);
    t3 += __shfl_xor(t3, 16); t3 += __shfl_xor(t3, 32);
    if (lane < 16) {
        ushort4 o = make_ushort4(f2b(t0), f2b(t1), f2b(t2), f2b(t3));
        *(ushort4*)(h + (size_t)wid * HID + d0) = o;
    }
}

// ---------------- readout ----------------

__global__ __launch_bounds__(256) void k_readout(const u16* __restrict__ h,
                                                 const int* __restrict__ graph_ids,
                                                 const int* __restrict__ is_root,
                                                 float* __restrict__ hg) {
    int wid = (blockIdx.x * 256 + threadIdx.x) >> 6;
    int lane = threadIdx.x & 63;
    if (is_root[wid]) {
        int g = graph_ids[wid];
        atomicAdd(&hg[g * HID + lane], b2f(h[(size_t)wid * HID + lane]));
    }
}

__global__ void k_out_gemm(const float* __restrict__ hg, const float* __restrict__ W,
                           const float* __restrict__ b, float* __restrict__ out) {
    int i = blockIdx.x * 256 + threadIdx.x;
    if (i >= NGRAPH * OUT_DIM) return;
    int g = i >> 5, o = i & 31;
    float acc = b[o];
    #pragma unroll
    for (int k = 0; k < HID; k++) acc += hg[g * HID + k] * W[k * OUT_DIM + o];
    out[i] = acc;
}

// ---------------- host ----------------

extern "C" void kernel_launch(void* const* d_in, const int* in_sizes, int n_in,
                              void* d_out, int out_size, void* d_ws, size_t ws_size,
                              hipStream_t stream) {
    const float* feat      = (const float*)d_in[0];
    const int*   src       = (const int*)d_in[1];
    const int*   dst       = (const int*)d_in[2];
    const int*   graph_ids = (const int*)d_in[3];
    const int*   is_root   = (const int*)d_in[4];
    const float* W_in      = (const float*)d_in[5];
    const float* b_in      = (const float*)d_in[6];
    const float* W_src     = (const float*)d_in[7];
    const float* b_src     = (const float*)d_in[8];
    const float* W_dst     = (const float*)d_in[9];
    const float* b_dst     = (const float*)d_in[10];
    const float* attn      = (const float*)d_in[11];
    const float* W_out     = (const float*)d_in[12];
    const float* b_out     = (const float*)d_in[13];
    float* out = (float*)d_out;

    char* base = (char*)d_ws;
    size_t off = 0;
    auto carve = [&](size_t bytes) -> char* {
        char* p = base + off;
        off = (off + bytes + 255) & ~(size_t)255;
        return p;
    };
    u16*   h0b     = (u16*)carve((size_t)N_NODES * HID * 2);
    u16*   hb      = (u16*)carve((size_t)N_NODES * HID * 2);
    u16*   fsfd    = (u16*)carve((size_t)N_NODES * 512 * 2);
    u16*   Wpack   = (u16*)carve(128 * 512 * 2);
    float* bcat    = (float*)carve(512 * 4);
    int*   csr_src = (int*)carve((size_t)N_EDGES * 4);
    int*   row_ptr = (int*)carve((size_t)N_NODES * 4);
    int*   bsum    = (int*)carve(SCAN_BLOCKS * 4);
    char*  zero0   = carve(0);
    int*   deg     = (int*)carve((size_t)N_NODES * 4);
    int*   cursor  = (int*)carve((size_t)N_NODES * 4);
    float* hg      = (float*)carve((size_t)NGRAPH * HID * 4);
    char*  zero1   = base + off;
    if (off > ws_size) return;  // workspace too small -> fail loudly

    hipMemsetAsync(zero0, 0, (size_t)(zero1 - zero0), stream);

    // graph prep
    k_build_wpack<<<256, 256, 0, stream>>>(W_src, b_src, W_dst, b_dst, Wpack, bcat);
    k_hist<<<(N_EDGES + 255) / 256, 256, 0, stream>>>(dst, deg);
    k_blocksum<<<SCAN_BLOCKS, 256, 0, stream>>>(deg, bsum);
    k_scanbsum<<<1, 64, 0, stream>>>(bsum);
    k_rowptr<<<SCAN_BLOCKS, 256, 0, stream>>>(deg, bsum, row_ptr);
    k_scatter<<<(N_EDGES + 255) / 256, 256, 0, stream>>>(src, dst, row_ptr, cursor, csr_src);

    // input projection
    k_in_gemm<<<N_NODES / 4, 256, 0, stream>>>(feat, W_in, b_in, h0b);

    const int gemm_grid = (N_NODES / 16 + 3) / 4;   // 3125 waves -> 782 blocks
    for (int layer = 0; layer < NUM_LAYERS; layer++) {
        const u16* hcur = (layer == 0) ? h0b : hb;
        k_gemm_mfma<<<gemm_grid, 256, 0, stream>>>(hcur, h0b, Wpack, bcat, fsfd);
        k_edge<<<N_NODES / 4, 256, 0, stream>>>(fsfd, attn, row_ptr, deg, csr_src, hb);
    }

    k_readout<<<N_NODES / 4, 256, 0, stream>>>(hb, graph_ids, is_root, hg);
    k_out_gemm<<<(NGRAPH * OUT_DIM + 255) / 256, 256, 0, stream>>>(hg, W_out, b_out, out);
}

// Round 4
// 1078.731 us; speedup vs baseline: 1.8243x; 1.1781x over previous
//
#include <hip/hip_runtime.h>
#include <math.h>

#define N_NODES 50000
#define N_EDGES 800000
#define IN_DIM  16
#define HID     64
#define NH      4
#define NGRAPH  128
#define OUT_DIM 32
#define NUM_LAYERS 8
#define NEG_SLOPE 0.2f

#define SCAN_BLOCKS ((N_NODES + 255) / 256)   // 196

typedef unsigned short u16;
typedef __attribute__((ext_vector_type(8))) short bf16x8;
typedef __attribute__((ext_vector_type(4))) float f32x4;

// float -> bf16 (round-nearest-even), bf16 -> float
static __device__ __forceinline__ u16 f2b(float f) {
    unsigned u = __float_as_uint(f);
    unsigned r = (u + 0x7fffu + ((u >> 16) & 1u)) >> 16;
    return (u16)r;
}
static __device__ __forceinline__ float b2f(u16 u) {
    return __uint_as_float(((unsigned)u) << 16);
}

// DPP lane-xor within quads (VALU-only cross-lane, keeps reduce off the LDS pipe)
#define DPP_XOR1(x) __uint_as_float((unsigned)__builtin_amdgcn_update_dpp(0, (int)__float_as_uint(x), 0xB1, 0xF, 0xF, true))
#define DPP_XOR2(x) __uint_as_float((unsigned)__builtin_amdgcn_update_dpp(0, (int)__float_as_uint(x), 0x4E, 0xF, 0xF, true))

// ---------------- setup kernels ----------------

// Pack Wcat=[W_src|W_dst] (fp32 [128][512]) into MFMA-fragment-ordered bf16:
// Wpack[((nt*4+kt)*64 + l)*8 + i] = Wcat[kt*32 + (l>>4)*8 + i][nt*16 + (l&15)]
// Also bcat[512] fp32.
__global__ void k_build_wpack(const float* __restrict__ Wsrc, const float* __restrict__ bsrc,
                              const float* __restrict__ Wdst, const float* __restrict__ bdst,
                              u16* __restrict__ Wpack, float* __restrict__ bcat) {
    int tid = blockIdx.x * 256 + threadIdx.x;   // 0..65535
    int i = tid & 7;
    int l = (tid >> 3) & 63;
    int rest = tid >> 9;          // 0..127
    int kt = rest & 3;
    int nt = rest >> 2;           // 0..31
    int k = kt * 32 + (l >> 4) * 8 + i;      // 0..127
    int col = nt * 16 + (l & 15);            // 0..511
    float v = (col < 256) ? Wsrc[k * 256 + col] : Wdst[k * 256 + (col - 256)];
    Wpack[tid] = f2b(v);
    if (tid < 512) bcat[tid] = (tid < 256) ? bsrc[tid] : bdst[tid - 256];
}

__global__ void k_hist(const int* __restrict__ dst, int* __restrict__ deg) {
    int e = blockIdx.x * 256 + threadIdx.x;
    if (e < N_EDGES) atomicAdd(&deg[dst[e]], 1);
}

__global__ void k_blocksum(const int* __restrict__ deg, int* __restrict__ bsum) {
    __shared__ int sm[256];
    int i = blockIdx.x * 256 + threadIdx.x;
    sm[threadIdx.x] = (i < N_NODES) ? deg[i] : 0;
    __syncthreads();
    for (int s = 128; s > 0; s >>= 1) {
        if (threadIdx.x < s) sm[threadIdx.x] += sm[threadIdx.x + s];
        __syncthreads();
    }
    if (threadIdx.x == 0) bsum[blockIdx.x] = sm[0];
}

__global__ void k_scanbsum(int* __restrict__ bsum) {
    if (threadIdx.x == 0 && blockIdx.x == 0) {
        int acc = 0;
        for (int b = 0; b < SCAN_BLOCKS; b++) { int t = bsum[b]; bsum[b] = acc; acc += t; }
    }
}

__global__ void k_rowptr(const int* __restrict__ deg, const int* __restrict__ bsum,
                         int* __restrict__ row_ptr) {
    __shared__ int sm[256];
    int i = blockIdx.x * 256 + threadIdx.x;
    int v = (i < N_NODES) ? deg[i] : 0;
    sm[threadIdx.x] = v;
    __syncthreads();
    for (int s = 1; s < 256; s <<= 1) {
        int t = (threadIdx.x >= (unsigned)s) ? sm[threadIdx.x - s] : 0;
        __syncthreads();
        sm[threadIdx.x] += t;
        __syncthreads();
    }
    if (i < N_NODES) row_ptr[i] = bsum[blockIdx.x] + sm[threadIdx.x] - v;  // exclusive
}

__global__ void k_scatter(const int* __restrict__ src, const int* __restrict__ dst,
                          const int* __restrict__ row_ptr, int* __restrict__ cursor,
                          int* __restrict__ csr_src) {
    int e = blockIdx.x * 256 + threadIdx.x;
    if (e < N_EDGES) {
        int d = dst[e];
        int pos = atomicAdd(&cursor[d], 1);
        csr_src[row_ptr[d] + pos] = src[e];
    }
}

// h0b = bf16(feat @ W_in + b_in)   one wave per node, lane = out col
__global__ __launch_bounds__(256) void k_in_gemm(const float* __restrict__ feat,
                                                 const float* __restrict__ W,
                                                 const float* __restrict__ b,
                                                 u16* __restrict__ h0b) {
    __shared__ float sW[IN_DIM * HID];
    __shared__ float sb[HID];
    int t = threadIdx.x;
    for (int i = t; i < IN_DIM * HID; i += 256) sW[i] = W[i];
    if (t < HID) sb[t] = b[t];
    __syncthreads();
    int wid = (blockIdx.x * 256 + t) >> 6;   // node
    int lane = t & 63;
    const float* f = feat + wid * IN_DIM;
    float acc = sb[lane];
    #pragma unroll
    for (int k = 0; k < IN_DIM; k++) acc += f[k] * sW[k * HID + lane];
    h0b[wid * HID + lane] = f2b(acc);
}

// ---------------- per-layer kernels ----------------

// fsfd[N][512] (bf16) = [h|h0] @ Wcat + bcat via MFMA 16x16x32 bf16.
#define ST_STRIDE 152   // shorts per staged C row (304 B: 16B-aligned, bank-spread)
__global__ __launch_bounds__(256) void k_gemm_mfma(const u16* __restrict__ hb,
                                                   const u16* __restrict__ h0b,
                                                   const u16* __restrict__ Wpack,
                                                   const float* __restrict__ bcat,
                                                   u16* __restrict__ fsfd) {
    __shared__ u16 smem[16384];   // 32 KB: W-group fragments, then reused for C staging
    int tid = threadIdx.x;
    int l = tid & 63, w = tid >> 6;
    int lr = l & 15, lg = l >> 4;
    int wave_gid = blockIdx.x * 4 + w;
    size_t row0 = (size_t)wave_gid * 16;
    bool valid = (row0 < N_NODES);            // waves fully in- or out-of-range (50000%16==0)
    u16* myst = smem + w * 4096;              // per-wave C staging slice (needs 16*152=2432)

    for (int g = 0; g < 4; g++) {
        __syncthreads();   // prior group's staging reads done before W overwrite
        {
            const bf16x8* src = (const bf16x8*)(Wpack) + g * 2048;
            bf16x8* dst = (bf16x8*)smem;
            #pragma unroll
            for (int it = 0; it < 8; it++) dst[it * 256 + tid] = src[it * 256 + tid];
        }
        __syncthreads();

        f32x4 acc[8];
        #pragma unroll
        for (int nt = 0; nt < 8; nt++) acc[nt] = (f32x4){0.f, 0.f, 0.f, 0.f};

        size_t arow = valid ? (row0 + lr) : 0;
        #pragma unroll
        for (int kt = 0; kt < 4; kt++) {
            const u16* A = (kt < 2) ? hb : h0b;
            bf16x8 a = *(const bf16x8*)(A + arow * HID + (kt & 1) * 32 + lg * 8);
            #pragma unroll
            for (int nt = 0; nt < 8; nt++) {
                bf16x8 bfr = *(const bf16x8*)(smem + nt * 2048 + kt * 512 + l * 8);
                acc[nt] = __builtin_amdgcn_mfma_f32_16x16x32_bf16(a, bfr, acc[nt], 0, 0, 0);
            }
        }
        __syncthreads();   // all waves done reading W before staging overwrites it

        // C/D layout: acc[nt][j] = C[row0 + lg*4 + j][g*128 + nt*16 + lr]
        #pragma unroll
        for (int nt = 0; nt < 8; nt++) {
            float bv = bcat[g * 128 + nt * 16 + lr];
            #pragma unroll
            for (int j = 0; j < 4; j++)
                myst[(lg * 4 + j) * ST_STRIDE + nt * 16 + lr] = f2b(acc[nt][j] + bv);
        }
        if (valid) {
            #pragma unroll
            for (int j = 0; j < 4; j++) {
                int rloc = j * 4 + lg;
                bf16x8 v = *(const bf16x8*)(myst + rloc * ST_STRIDE + lr * 8);
                *(bf16x8*)(fsfd + (row0 + rloc) * 512 + g * 128 + lr * 8) = v;
            }
        }
    }
}

// Per dst node: online segment-softmax + weighted aggregation + tanh-headsum.
// One wave per node, 4 edge-groups x 16 lanes. Group g owns edges g, g+4, ...
// with an independent online state; lane ll covers row elements ll*16..+15
// (head = ll>>2). Logit reduce = 2 DPP quad-xors. Flash-merge + fast tanh tail.
__global__ __launch_bounds__(256) void k_edge(const u16* __restrict__ fsfd,
                                              const float* __restrict__ attn,
                                              const int* __restrict__ row_ptr,
                                              const int* __restrict__ deg,
                                              const int* __restrict__ csr_src,
                                              u16* __restrict__ h) {
    int wid = (blockIdx.x * 256 + threadIdx.x) >> 6;   // node (grid exact)
    int lane = threadIdx.x & 63;
    int g  = lane >> 4;       // edge group
    int ll = lane & 15;       // element slot
    const size_t ebase = (size_t)ll * 16;

    // attn for this lane's 16 elements, pre-scaled by log2(e) -> exp2 domain
    float an[16];
    {
        const float* ap = attn + ll * 16;
        #pragma unroll
        for (int e = 0; e < 16; e++) an[e] = ap[e] * 1.44269504f;
    }
    // fd for this node's 16 elements
    float fd[16];
    {
        const u16* p = fsfd + (size_t)wid * 512 + 256 + ebase;
        uint4 a = *(const uint4*)p, b = *(const uint4*)(p + 8);
        unsigned ww[8] = {a.x, a.y, a.z, a.w, b.x, b.y, b.z, b.w};
        #pragma unroll
        for (int q = 0; q < 8; q++) {
            fd[2*q]   = __uint_as_float(ww[q] << 16);
            fd[2*q+1] = __uint_as_float(ww[q] & 0xffff0000u);
        }
    }

    float m = -3.0e38f, denom = 0.f;
    float agg[16];
    #pragma unroll
    for (int e = 0; e < 16; e++) agg[e] = 0.f;

    int r0 = row_ptr[wid], dg = deg[wid];
    for (int i = g; i < dg; i += 4) {
        int s = csr_src[r0 + i];
        const u16* p = fsfd + (size_t)s * 512 + ebase;
        uint4 a = *(const uint4*)p, b = *(const uint4*)(p + 8);
        float f[16];
        {
            unsigned ww[8] = {a.x, a.y, a.z, a.w, b.x, b.y, b.z, b.w};
            #pragma unroll
            for (int q = 0; q < 8; q++) {
                f[2*q]   = __uint_as_float(ww[q] << 16);
                f[2*q+1] = __uint_as_float(ww[q] & 0xffff0000u);
            }
        }
        float p0 = 0.f, p1 = 0.f;
        #pragma unroll
        for (int e = 0; e < 16; e += 2) {
            float e0 = f[e]   + fd[e];
            float e1 = f[e+1] + fd[e+1];
            p0 = fmaf(fmaxf(e0, e0 * NEG_SLOPE), an[e],   p0);   // leaky = max(x, 0.2x)
            p1 = fmaf(fmaxf(e1, e1 * NEG_SLOPE), an[e+1], p1);
        }
        float pp = p0 + p1;
        pp += DPP_XOR1(pp);
        pp += DPP_XOR2(pp);          // sum over the 4 lanes of this head
        float nm = fmaxf(m, pp);
        float rs = exp2f(m - nm);    // 0 on first edge (m = -3e38)
        float c  = exp2f(pp - nm);
        #pragma unroll
        for (int e = 0; e < 16; e++) agg[e] = fmaf(agg[e], rs, c * f[e]);
        denom = fmaf(denom, rs, c);
        m = nm;
    }

    // flash-merge the 4 groups' states (butterfly xor 16, then 32)
    #pragma unroll
    for (int mask = 16; mask <= 32; mask <<= 1) {
        float mo = __shfl_xor(m, mask);
        float dn = __shfl_xor(denom, mask);
        float nm = fmaxf(m, mo);
        float sa = exp2f(m - nm);
        float sb = exp2f(mo - nm);
        denom = denom * sa + dn * sb;
        #pragma unroll
        for (int e = 0; e < 16; e++)
            agg[e] = agg[e] * sa + __shfl_xor(agg[e], mask) * sb;
        m = nm;
    }

    float inv = denom > 0.f ? __builtin_amdgcn_rcpf(denom) : 0.f;
    float t[16];
    #pragma unroll
    for (int e = 0; e < 16; e++) {
        float x = agg[e] * inv;
        // tanh(x) = 1 - 2/(exp2(x*2*log2e) + 1)
        float E = exp2f(x * 2.885390082f);
        float r = __builtin_amdgcn_rcpf(E + 1.f);
        t[e] = fmaf(-2.f, r, 1.f);
        t[e] += __shfl_xor(t[e], 4);   // sum over 4 heads
        t[e] += __shfl_xor(t[e], 8);
    }
    if (lane < 4) {
        unsigned o[8];
        #pragma unroll
        for (int q = 0; q < 8; q++)
            o[q] = (unsigned)f2b(t[2*q]) | ((unsigned)f2b(t[2*q+1]) << 16);
        u16* hp = h + (size_t)wid * 64 + lane * 16;
        *(uint4*)hp       = make_uint4(o[0], o[1], o[2], o[3]);
        *(uint4*)(hp + 8) = make_uint4(o[4], o[5], o[6], o[7]);
    }
}

// ---------------- readout ----------------

__global__ __launch_bounds__(256) void k_readout(const u16* __restrict__ h,
                                                 const int* __restrict__ graph_ids,
                                                 const int* __restrict__ is_root,
                                                 float* __restrict__ hg) {
    int wid = (blockIdx.x * 256 + threadIdx.x) >> 6;
    int lane = threadIdx.x & 63;
    if (is_root[wid]) {
        int g = graph_ids[wid];
        atomicAdd(&hg[g * HID + lane], b2f(h[(size_t)wid * HID + lane]));
    }
}

__global__ void k_out_gemm(const float* __restrict__ hg, const float* __restrict__ W,
                           const float* __restrict__ b, float* __restrict__ out) {
    int i = blockIdx.x * 256 + threadIdx.x;
    if (i >= NGRAPH * OUT_DIM) return;
    int g = i >> 5, o = i & 31;
    float acc = b[o];
    #pragma unroll
    for (int k = 0; k < HID; k++) acc += hg[g * HID + k] * W[k * OUT_DIM + o];
    out[i] = acc;
}

// ---------------- host ----------------

extern "C" void kernel_launch(void* const* d_in, const int* in_sizes, int n_in,
                              void* d_out, int out_size, void* d_ws, size_t ws_size,
                              hipStream_t stream) {
    const float* feat      = (const float*)d_in[0];
    const int*   src       = (const int*)d_in[1];
    const int*   dst       = (const int*)d_in[2];
    const int*   graph_ids = (const int*)d_in[3];
    const int*   is_root   = (const int*)d_in[4];
    const float* W_in      = (const float*)d_in[5];
    const float* b_in      = (const float*)d_in[6];
    const float* W_src     = (const float*)d_in[7];
    const float* b_src     = (const float*)d_in[8];
    const float* W_dst     = (const float*)d_in[9];
    const float* b_dst     = (const float*)d_in[10];
    const float* attn      = (const float*)d_in[11];
    const float* W_out     = (const float*)d_in[12];
    const float* b_out     = (const float*)d_in[13];
    float* out = (float*)d_out;

    char* base = (char*)d_ws;
    size_t off = 0;
    auto carve = [&](size_t bytes) -> char* {
        char* p = base + off;
        off = (off + bytes + 255) & ~(size_t)255;
        return p;
    };
    u16*   h0b     = (u16*)carve((size_t)N_NODES * HID * 2);
    u16*   hb      = (u16*)carve((size_t)N_NODES * HID * 2);
    u16*   fsfd    = (u16*)carve((size_t)N_NODES * 512 * 2);
    u16*   Wpack   = (u16*)carve(128 * 512 * 2);
    float* bcat    = (float*)carve(512 * 4);
    int*   csr_src = (int*)carve((size_t)N_EDGES * 4);
    int*   row_ptr = (int*)carve((size_t)N_NODES * 4);
    int*   bsum    = (int*)carve(SCAN_BLOCKS * 4);
    char*  zero0   = carve(0);
    int*   deg     = (int*)carve((size_t)N_NODES * 4);
    int*   cursor  = (int*)carve((size_t)N_NODES * 4);
    float* hg      = (float*)carve((size_t)NGRAPH * HID * 4);
    char*  zero1   = base + off;
    if (off > ws_size) return;  // workspace too small -> fail loudly

    hipMemsetAsync(zero0, 0, (size_t)(zero1 - zero0), stream);

    // graph prep
    k_build_wpack<<<256, 256, 0, stream>>>(W_src, b_src, W_dst, b_dst, Wpack, bcat);
    k_hist<<<(N_EDGES + 255) / 256, 256, 0, stream>>>(dst, deg);
    k_blocksum<<<SCAN_BLOCKS, 256, 0, stream>>>(deg, bsum);
    k_scanbsum<<<1, 64, 0, stream>>>(bsum);
    k_rowptr<<<SCAN_BLOCKS, 256, 0, stream>>>(deg, bsum, row_ptr);
    k_scatter<<<(N_EDGES + 255) / 256, 256, 0, stream>>>(src, dst, row_ptr, cursor, csr_src);

    // input projection
    k_in_gemm<<<N_NODES / 4, 256, 0, stream>>>(feat, W_in, b_in, h0b);

    const int gemm_grid = (N_NODES / 16 + 3) / 4;   // 3125 waves -> 782 blocks
    for (int layer = 0; layer < NUM_LAYERS; layer++) {
        const u16* hcur = (layer == 0) ? h0b : hb;
        k_gemm_mfma<<<gemm_grid, 256, 0, stream>>>(hcur, h0b, Wpack, bcat, fsfd);
        k_edge<<<N_NODES / 4, 256, 0, stream>>>(fsfd, attn, row_ptr, deg, csr_src, hb);
    }

    k_readout<<<N_NODES / 4, 256, 0, stream>>>(hb, graph_ids, is_root, hg);
    k_out_gemm<<<(NGRAPH * OUT_DIM + 255) / 256, 256, 0, stream>>>(hg, W_out, b_out, out);
}

// Round 5
// 948.652 us; speedup vs baseline: 2.0745x; 1.1371x over previous
//
#include <hip/hip_runtime.h>
#include <math.h>

#define N_NODES 50000
#define N_EDGES 800000
#define IN_DIM  16
#define HID     64
#define NH      4
#define NGRAPH  128
#define OUT_DIM 32
#define NUM_LAYERS 8
#define NEG_SLOPE 0.2f

#define SCAN_BLOCKS ((N_NODES + 255) / 256)   // 196

typedef unsigned short u16;
typedef _Float16 h2   __attribute__((ext_vector_type(2)));
typedef _Float16 f16x8 __attribute__((ext_vector_type(8)));
typedef __attribute__((ext_vector_type(4))) float f32x4;

static __device__ __forceinline__ u16 f2h(float f) {
    _Float16 h = (_Float16)f; u16 r; __builtin_memcpy(&r, &h, 2); return r;
}
static __device__ __forceinline__ float h2f_lo(unsigned w) {
    _Float16 h; u16 u = (u16)w; __builtin_memcpy(&h, &u, 2); return (float)h;
}
static __device__ __forceinline__ h2 shfl_h2(h2 v, int mask) {
    int i; __builtin_memcpy(&i, &v, 4); i = __shfl_xor(i, mask);
    h2 r; __builtin_memcpy(&r, &i, 4); return r;
}
static __device__ __forceinline__ h2 bcast_h2(float f) {
    _Float16 h = (_Float16)f; h2 r; r[0] = h; r[1] = h; return r;
}

// DPP lane-xor within quads (VALU-only cross-lane reduce)
#define DPP_XOR1(x) __uint_as_float((unsigned)__builtin_amdgcn_update_dpp(0, (int)__float_as_uint(x), 0xB1, 0xF, 0xF, true))
#define DPP_XOR2(x) __uint_as_float((unsigned)__builtin_amdgcn_update_dpp(0, (int)__float_as_uint(x), 0x4E, 0xF, 0xF, true))

// ---------------- setup kernels ----------------

// Pack Wcat=[W_src|W_dst] (fp32 [128][512]) into MFMA-fragment-ordered f16:
// Wpack[((nt*4+kt)*64 + l)*8 + i] = Wcat[kt*32 + (l>>4)*8 + i][nt*16 + (l&15)]
// Also bcat[512] f32 and an_h[256] = f16(attn * log2e).
__global__ void k_build_wpack(const float* __restrict__ Wsrc, const float* __restrict__ bsrc,
                              const float* __restrict__ Wdst, const float* __restrict__ bdst,
                              const float* __restrict__ attn,
                              u16* __restrict__ Wpack, float* __restrict__ bcat,
                              u16* __restrict__ an_h) {
    int tid = blockIdx.x * 256 + threadIdx.x;   // 0..65535
    int i = tid & 7;
    int l = (tid >> 3) & 63;
    int rest = tid >> 9;          // 0..127
    int kt = rest & 3;
    int nt = rest >> 2;           // 0..31
    int k = kt * 32 + (l >> 4) * 8 + i;      // 0..127
    int col = nt * 16 + (l & 15);            // 0..511
    float v = (col < 256) ? Wsrc[k * 256 + col] : Wdst[k * 256 + (col - 256)];
    Wpack[tid] = f2h(v);
    if (tid < 512) bcat[tid] = (tid < 256) ? bsrc[tid] : bdst[tid - 256];
    if (tid < 256) an_h[tid] = f2h(attn[tid] * 1.44269504f);   // fold log2(e)
}

__global__ void k_hist(const int* __restrict__ dst, int* __restrict__ deg) {
    int e = blockIdx.x * 256 + threadIdx.x;
    if (e < N_EDGES) atomicAdd(&deg[dst[e]], 1);
}

__global__ void k_blocksum(const int* __restrict__ deg, int* __restrict__ bsum) {
    __shared__ int sm[256];
    int i = blockIdx.x * 256 + threadIdx.x;
    sm[threadIdx.x] = (i < N_NODES) ? deg[i] : 0;
    __syncthreads();
    for (int s = 128; s > 0; s >>= 1) {
        if (threadIdx.x < s) sm[threadIdx.x] += sm[threadIdx.x + s];
        __syncthreads();
    }
    if (threadIdx.x == 0) bsum[blockIdx.x] = sm[0];
}

__global__ void k_scanbsum(int* __restrict__ bsum) {
    if (threadIdx.x == 0 && blockIdx.x == 0) {
        int acc = 0;
        for (int b = 0; b < SCAN_BLOCKS; b++) { int t = bsum[b]; bsum[b] = acc; acc += t; }
    }
}

__global__ void k_rowptr(const int* __restrict__ deg, const int* __restrict__ bsum,
                         int* __restrict__ row_ptr) {
    __shared__ int sm[256];
    int i = blockIdx.x * 256 + threadIdx.x;
    int v = (i < N_NODES) ? deg[i] : 0;
    sm[threadIdx.x] = v;
    __syncthreads();
    for (int s = 1; s < 256; s <<= 1) {
        int t = (threadIdx.x >= (unsigned)s) ? sm[threadIdx.x - s] : 0;
        __syncthreads();
        sm[threadIdx.x] += t;
        __syncthreads();
    }
    if (i < N_NODES) row_ptr[i] = bsum[blockIdx.x] + sm[threadIdx.x] - v;  // exclusive
}

__global__ void k_scatter(const int* __restrict__ src, const int* __restrict__ dst,
                          const int* __restrict__ row_ptr, int* __restrict__ cursor,
                          int* __restrict__ csr_src) {
    int e = blockIdx.x * 256 + threadIdx.x;
    if (e < N_EDGES) {
        int d = dst[e];
        int pos = atomicAdd(&cursor[d], 1);
        csr_src[row_ptr[d] + pos] = src[e];
    }
}

// h0h = f16(feat @ W_in + b_in)   one wave per node, lane = out col
__global__ __launch_bounds__(256) void k_in_gemm(const float* __restrict__ feat,
                                                 const float* __restrict__ W,
                                                 const float* __restrict__ b,
                                                 u16* __restrict__ h0h) {
    __shared__ float sW[IN_DIM * HID];
    __shared__ float sb[HID];
    int t = threadIdx.x;
    for (int i = t; i < IN_DIM * HID; i += 256) sW[i] = W[i];
    if (t < HID) sb[t] = b[t];
    __syncthreads();
    int wid = (blockIdx.x * 256 + t) >> 6;   // node
    int lane = t & 63;
    const float* f = feat + wid * IN_DIM;
    float acc = sb[lane];
    #pragma unroll
    for (int k = 0; k < IN_DIM; k++) acc += f[k] * sW[k * HID + lane];
    h0h[wid * HID + lane] = f2h(acc);
}

// ---------------- per-layer kernels ----------------

// fsfd[N][512] (f16) = [h|h0] @ Wcat + bcat via MFMA 16x16x32 f16.
// Block = 4 waves; each wave computes 2 row-tiles (32 rows), 4 col-groups of 128.
#define ST_STRIDE 152   // u16 per staged C row (304 B: 16B-aligned, bank-spread)
__global__ __launch_bounds__(256) void k_gemm_mfma(const u16* __restrict__ hb,
                                                   const u16* __restrict__ h0b,
                                                   const u16* __restrict__ Wpack,
                                                   const float* __restrict__ bcat,
                                                   u16* __restrict__ fsfd) {
    __shared__ u16 smem[16384];   // 32 KB: W-group fragments, then reused for C staging
    int tid = threadIdx.x;
    int l = tid & 63, w = tid >> 6;
    int lr = l & 15, lg = l >> 4;
    int wave_gid = blockIdx.x * 4 + w;
    size_t rbase = (size_t)wave_gid * 32;
    u16* myst = smem + w * 4096;              // per-wave C staging slice (16*152=2432 used)

    for (int g = 0; g < 4; g++) {
        __syncthreads();   // prior group's staging reads done before W overwrite
        {
            const f16x8* src = (const f16x8*)(Wpack) + g * 2048;
            f16x8* dst = (f16x8*)smem;
            #pragma unroll
            for (int it = 0; it < 8; it++) dst[it * 256 + tid] = src[it * 256 + tid];
        }
        __syncthreads();

        f32x4 acc[2][8];
        #pragma unroll
        for (int rt = 0; rt < 2; rt++)
            #pragma unroll
            for (int nt = 0; nt < 8; nt++) acc[rt][nt] = (f32x4){0.f, 0.f, 0.f, 0.f};

        #pragma unroll
        for (int kt = 0; kt < 4; kt++) {
            const u16* A = (kt < 2) ? hb : h0b;
            int koff = (kt & 1) * 32 + lg * 8;
            f16x8 a0, a1;
            {
                size_t r0 = rbase + lr;        // tile 0
                size_t r1 = rbase + 16 + lr;   // tile 1
                if (r0 >= N_NODES) r0 = 0;
                if (r1 >= N_NODES) r1 = 0;
                a0 = *(const f16x8*)(A + r0 * HID + koff);
                a1 = *(const f16x8*)(A + r1 * HID + koff);
            }
            #pragma unroll
            for (int nt = 0; nt < 8; nt++) {
                f16x8 bfr = *(const f16x8*)(smem + nt * 2048 + kt * 512 + l * 8);
                acc[0][nt] = __builtin_amdgcn_mfma_f32_16x16x32_f16(a0, bfr, acc[0][nt], 0, 0, 0);
                acc[1][nt] = __builtin_amdgcn_mfma_f32_16x16x32_f16(a1, bfr, acc[1][nt], 0, 0, 0);
            }
        }
        __syncthreads();   // all waves done reading W before staging overwrites it

        // C/D layout: acc[rt][nt][j] = C[rbase + rt*16 + lg*4 + j][g*128 + nt*16 + lr]
        #pragma unroll
        for (int rt = 0; rt < 2; rt++) {
            size_t row0 = rbase + rt * 16;
            if (row0 >= N_NODES) break;
            #pragma unroll
            for (int nt = 0; nt < 8; nt++) {
                float bv = bcat[g * 128 + nt * 16 + lr];
                #pragma unroll
                for (int j = 0; j < 4; j++)
                    myst[(lg * 4 + j) * ST_STRIDE + nt * 16 + lr] = f2h(acc[rt][nt][j] + bv);
            }
            #pragma unroll
            for (int j = 0; j < 4; j++) {
                int rloc = j * 4 + lg;
                f16x8 v = *(const f16x8*)(myst + rloc * ST_STRIDE + lr * 8);
                *(f16x8*)(fsfd + (row0 + rloc) * 512 + g * 128 + lr * 8) = v;
            }
        }
    }
}

// Per dst node: online segment-softmax + weighted aggregation + tanh-headsum.
// One wave per node, 4 edge-groups x 16 lanes; packed-f16 inner loop.
// Lane ll covers fs-row elements ll*16..+15 (head = ll>>2).
__global__ __launch_bounds__(256) void k_edge(const u16* __restrict__ fsfd,
                                              const u16* __restrict__ an_h,
                                              const int* __restrict__ row_ptr,
                                              const int* __restrict__ deg,
                                              const int* __restrict__ csr_src,
                                              u16* __restrict__ h) {
    int wid = (blockIdx.x * 256 + threadIdx.x) >> 6;   // node (grid exact)
    int lane = threadIdx.x & 63;
    int g  = lane >> 4;       // edge group
    int ll = lane & 15;       // element slot
    const size_t ebase = (size_t)ll * 16;

    h2 an[8], fdh[8];
    {
        const uint4* ap = (const uint4*)(an_h + ebase);
        uint4 a0 = ap[0], a1 = ap[1];
        unsigned aw[8] = {a0.x, a0.y, a0.z, a0.w, a1.x, a1.y, a1.z, a1.w};
        __builtin_memcpy(an, aw, 32);
        const uint4* fp = (const uint4*)(fsfd + (size_t)wid * 512 + 256 + ebase);
        uint4 b0 = fp[0], b1 = fp[1];
        unsigned fw[8] = {b0.x, b0.y, b0.z, b0.w, b1.x, b1.y, b1.z, b1.w};
        __builtin_memcpy(fdh, fw, 32);
    }
    const h2 slope2 = {(_Float16)NEG_SLOPE, (_Float16)NEG_SLOPE};

    float m = -3.0e38f, denom = 0.f;
    h2 agg[8];
    #pragma unroll
    for (int q = 0; q < 8; q++) agg[q] = (h2){(_Float16)0.f, (_Float16)0.f};

    int r0 = row_ptr[wid], dg = deg[wid];
    for (int i = g; i < dg; i += 4) {
        int s = csr_src[r0 + i];
        const uint4* P = (const uint4*)(fsfd + (size_t)s * 512 + ebase);
        uint4 A = P[0], B = P[1];
        h2 f[8];
        {
            unsigned fw[8] = {A.x, A.y, A.z, A.w, B.x, B.y, B.z, B.w};
            __builtin_memcpy(f, fw, 32);
        }
        float p = 0.f;
        #pragma unroll
        for (int q = 0; q < 8; q++) {
            h2 e  = f[q] + fdh[q];                         // v_pk_add_f16
            h2 lk = __builtin_elementwise_max(e, e * slope2);  // pk_mul + pk_max
#if __has_builtin(__builtin_amdgcn_fdot2)
            p = __builtin_amdgcn_fdot2(lk, an[q], p, false);   // v_dot2_f32_f16
#else
            h2 pr = lk * an[q];
            p += (float)pr[0] + (float)pr[1];
#endif
        }
        p += DPP_XOR1(p);
        p += DPP_XOR2(p);            // sum over the 4 lanes of this head
        float nm = fmaxf(m, p);
        float rs = exp2f(m - nm);    // 0 on first edge
        float c  = exp2f(p - nm);
        h2 rs2 = bcast_h2(rs), c2 = bcast_h2(c);
        #pragma unroll
        for (int q = 0; q < 8; q++) agg[q] = agg[q] * rs2 + f[q] * c2;  // pk_mul+pk_fma
        denom = fmaf(denom, rs, c);
        m = nm;
    }

    // flash-merge the 4 groups' states (butterfly xor 16, then 32)
    #pragma unroll
    for (int mask = 16; mask <= 32; mask <<= 1) {
        float mo = __shfl_xor(m, mask);
        float dn = __shfl_xor(denom, mask);
        float nm = fmaxf(m, mo);
        float sa = exp2f(m - nm);
        float sb = exp2f(mo - nm);
        h2 sa2 = bcast_h2(sa), sb2 = bcast_h2(sb);
        denom = denom * sa + dn * sb;
        #pragma unroll
        for (int q = 0; q < 8; q++)
            agg[q] = agg[q] * sa2 + shfl_h2(agg[q], mask) * sb2;
        m = nm;
    }

    float inv = denom > 0.f ? __builtin_amdgcn_rcpf(denom) : 0.f;
    float t[16];
    #pragma unroll
    for (int q = 0; q < 8; q++) {
        #pragma unroll
        for (int j = 0; j < 2; j++) {
            float x = (float)agg[q][j] * inv;
            float E = exp2f(x * 2.885390082f);     // tanh(x) = 1 - 2/(e^{2x}+1)
            float r = __builtin_amdgcn_rcpf(E + 1.f);
            float v = fmaf(-2.f, r, 1.f);
            v += __shfl_xor(v, 4);   // sum over 4 heads
            v += __shfl_xor(v, 8);
            t[q * 2 + j] = v;
        }
    }
    if (lane < 4) {
        unsigned o[8];
        #pragma unroll
        for (int q = 0; q < 8; q++)
            o[q] = (unsigned)f2h(t[2*q]) | ((unsigned)f2h(t[2*q+1]) << 16);
        u16* hp = h + (size_t)wid * 64 + lane * 16;
        *(uint4*)hp       = make_uint4(o[0], o[1], o[2], o[3]);
        *(uint4*)(hp + 8) = make_uint4(o[4], o[5], o[6], o[7]);
    }
}

// ---------------- readout ----------------

__global__ __launch_bounds__(256) void k_readout(const u16* __restrict__ h,
                                                 const int* __restrict__ graph_ids,
                                                 const int* __restrict__ is_root,
                                                 float* __restrict__ hg) {
    int wid = (blockIdx.x * 256 + threadIdx.x) >> 6;
    int lane = threadIdx.x & 63;
    if (is_root[wid]) {
        int g = graph_ids[wid];
        atomicAdd(&hg[g * HID + lane], h2f_lo(h[(size_t)wid * HID + lane]));
    }
}

__global__ void k_out_gemm(const float* __restrict__ hg, const float* __restrict__ W,
                           const float* __restrict__ b, float* __restrict__ out) {
    int i = blockIdx.x * 256 + threadIdx.x;
    if (i >= NGRAPH * OUT_DIM) return;
    int g = i >> 5, o = i & 31;
    float acc = b[o];
    #pragma unroll
    for (int k = 0; k < HID; k++) acc += hg[g * HID + k] * W[k * OUT_DIM + o];
    out[i] = acc;
}

// ---------------- host ----------------

extern "C" void kernel_launch(void* const* d_in, const int* in_sizes, int n_in,
                              void* d_out, int out_size, void* d_ws, size_t ws_size,
                              hipStream_t stream) {
    const float* feat      = (const float*)d_in[0];
    const int*   src       = (const int*)d_in[1];
    const int*   dst       = (const int*)d_in[2];
    const int*   graph_ids = (const int*)d_in[3];
    const int*   is_root   = (const int*)d_in[4];
    const float* W_in      = (const float*)d_in[5];
    const float* b_in      = (const float*)d_in[6];
    const float* W_src     = (const float*)d_in[7];
    const float* b_src     = (const float*)d_in[8];
    const float* W_dst     = (const float*)d_in[9];
    const float* b_dst     = (const float*)d_in[10];
    const float* attn      = (const float*)d_in[11];
    const float* W_out     = (const float*)d_in[12];
    const float* b_out     = (const float*)d_in[13];
    float* out = (float*)d_out;

    char* base = (char*)d_ws;
    size_t off = 0;
    auto carve = [&](size_t bytes) -> char* {
        char* p = base + off;
        off = (off + bytes + 255) & ~(size_t)255;
        return p;
    };
    u16*   h0b     = (u16*)carve((size_t)N_NODES * HID * 2);
    u16*   hb      = (u16*)carve((size_t)N_NODES * HID * 2);
    u16*   fsfd    = (u16*)carve((size_t)N_NODES * 512 * 2);
    u16*   Wpack   = (u16*)carve(128 * 512 * 2);
    float* bcat    = (float*)carve(512 * 4);
    u16*   an_h    = (u16*)carve(256 * 2);
    int*   csr_src = (int*)carve((size_t)N_EDGES * 4);
    int*   row_ptr = (int*)carve((size_t)N_NODES * 4);
    int*   bsum    = (int*)carve(SCAN_BLOCKS * 4);
    char*  zero0   = carve(0);
    int*   deg     = (int*)carve((size_t)N_NODES * 4);
    int*   cursor  = (int*)carve((size_t)N_NODES * 4);
    float* hg      = (float*)carve((size_t)NGRAPH * HID * 4);
    char*  zero1   = base + off;
    if (off > ws_size) return;  // workspace too small -> fail loudly

    hipMemsetAsync(zero0, 0, (size_t)(zero1 - zero0), stream);

    // graph prep
    k_build_wpack<<<256, 256, 0, stream>>>(W_src, b_src, W_dst, b_dst, attn, Wpack, bcat, an_h);
    k_hist<<<(N_EDGES + 255) / 256, 256, 0, stream>>>(dst, deg);
    k_blocksum<<<SCAN_BLOCKS, 256, 0, stream>>>(deg, bsum);
    k_scanbsum<<<1, 64, 0, stream>>>(bsum);
    k_rowptr<<<SCAN_BLOCKS, 256, 0, stream>>>(deg, bsum, row_ptr);
    k_scatter<<<(N_EDGES + 255) / 256, 256, 0, stream>>>(src, dst, row_ptr, cursor, csr_src);

    // input projection
    k_in_gemm<<<N_NODES / 4, 256, 0, stream>>>(feat, W_in, b_in, h0b);

    const int gemm_grid = (N_NODES + 127) / 128;   // 391 blocks (4 waves x 32 rows)
    for (int layer = 0; layer < NUM_LAYERS; layer++) {
        const u16* hcur = (layer == 0) ? h0b : hb;
        k_gemm_mfma<<<gemm_grid, 256, 0, stream>>>(hcur, h0b, Wpack, bcat, fsfd);
        k_edge<<<N_NODES / 4, 256, 0, stream>>>(fsfd, an_h, row_ptr, deg, csr_src, hb);
    }

    k_readout<<<N_NODES / 4, 256, 0, stream>>>(hb, graph_ids, is_root, hg);
    k_out_gemm<<<(NGRAPH * OUT_DIM + 255) / 256, 256, 0, stream>>>(hg, W_out, b_out, out);
}